// Round 19
// baseline (527.908 us; speedup 1.0000x reference)
//
#include <hip/hip_runtime.h>
#include <math.h>

#define DEV __device__ __forceinline__

#define NN 10000
#define NE 160000
#define DH 64
#define SC 31
#define VC 54
#define TC 50
#define NIR 135
#define FEAT 60
#define ENT 4096     // radial table entries
#define ROWF 140     // table row floats: S@0(31) pad | V@32(54) pad | T@88(50) pad
#define ROW4 35      // table row float4s
#define DCV 4.0f     // rational map scale: u = d/(DCV+d)

DEV float rcpf(float x) { return __builtin_amdgcn_rcpf(x); }

DEV float geluf(float x) {
    float u = 0.7978845608028654f * (x + 0.044715f * x * x * x);
    u = fminf(fmaxf(u, -9.f), 9.f);
    float e = __expf(2.f * u);
    float th = (e - 1.f) * rcpf(e + 1.f);
    return 0.5f * x * (1.f + th);
}
DEV float sigmoidf_(float x) { return rcpf(1.f + __expf(-x)); }

// ================= CSR build (once per launch) =================
__global__ __launch_bounds__(256) void csr_hist(const int* __restrict__ rcv,
                                                int* __restrict__ counts,
                                                int* __restrict__ rank) {
    int e = blockIdx.x * 256 + threadIdx.x;
    if (e >= NE) return;
    rank[e] = atomicAdd(&counts[rcv[e]], 1);
}

__global__ __launch_bounds__(1024) void csr_scan(const int* __restrict__ counts,
                                                 int* __restrict__ offs) {
    __shared__ int buf[1024];
    __shared__ int carry_s;
    if (threadIdx.x == 0) carry_s = 0;
    __syncthreads();
    for (int base = 0; base < 10240; base += 1024) {
        int i = base + threadIdx.x;
        int v = (i < NN) ? counts[i] : 0;
        buf[threadIdx.x] = v;
        __syncthreads();
        for (int off = 1; off < 1024; off <<= 1) {
            int t = (threadIdx.x >= off) ? buf[threadIdx.x - off] : 0;
            __syncthreads();
            buf[threadIdx.x] += t;
            __syncthreads();
        }
        int cbase = carry_s;
        int incl = buf[threadIdx.x];
        if (i < NN) offs[i] = cbase + incl - v;
        int total = buf[1023];
        __syncthreads();
        if (threadIdx.x == 0) carry_s = cbase + total;
        __syncthreads();
    }
    if (threadIdx.x == 0) offs[NN] = carry_s;
}

__global__ __launch_bounds__(256) void csr_fill(const int* __restrict__ rcv,
                                                const int* __restrict__ offs,
                                                const int* __restrict__ rank,
                                                int* __restrict__ elist) {
    int e = blockIdx.x * 256 + threadIdx.x;
    if (e >= NE) return;
    elist[offs[rcv[e]] + rank[e]] = e;
}

// ================= W3 transpose (once per launch) =================
__global__ __launch_bounds__(256) void w3t_kernel(const float* __restrict__ Wr3,
                                                  float* __restrict__ W3t) {
    int t = blockIdx.x * 256 + threadIdx.x;
    if (t >= 3 * NIR * DH) return;
    int k = t / (NIR * DH), r = t % (NIR * DH);
    int i = r / DH, j = r % DH;
    W3t[t] = Wr3[k * DH * NIR + j * NIR + i];
}

// ================= table: radial MLP on rational grid, ONE WAVE PER ENTRY =================
__global__ __launch_bounds__(256) void table_kernel(
    const float* __restrict__ W0, const float* __restrict__ W1,
    const float* __restrict__ W2, const float* __restrict__ W3t,
    float* __restrict__ table)
{
    __shared__ float hsh[4][DH];
    int wid = threadIdx.x >> 6;
    int lane = threadIdx.x & 63;
    int i = blockIdx.x * 4 + wid;

    float u = (float)i / (float)ENT;
    float ds = fmaxf(DCV * u * rcpf(1.f - u), 1e-9f);
    float rinv = 1.f / ds;
    float R4[4];
#pragma unroll
    for (int b = 0; b < 4; b++)
        R4[b] = sinf((float)(b + 1) * 1.5707963267948966f * ds) * rinv;

    float h = geluf((R4[0] * W0[lane] + R4[1] * W0[DH + lane] +
                     R4[2] * W0[2 * DH + lane] + R4[3] * W0[3 * DH + lane]) * 0.5f);
    hsh[wid][lane] = h;
    __syncthreads();

    {
        float acc = 0.f;
#pragma unroll
        for (int j = 0; j < DH; j++) acc += hsh[wid][j] * W1[j * DH + lane];
        h = geluf(acc * 0.125f);
    }
    __syncthreads();
    hsh[wid][lane] = h;
    __syncthreads();

    {
        float acc = 0.f;
#pragma unroll
        for (int j = 0; j < DH; j++) acc += hsh[wid][j] * W2[j * DH + lane];
        h = geluf(acc * 0.125f);
    }
    __syncthreads();
    hsh[wid][lane] = h;
    __syncthreads();

    float* trow = table + (size_t)i * ROWF;
#pragma unroll
    for (int rb = 0; rb < 3; rb++) {
        int r = rb * 64 + lane;
        if (r < NIR) {
            const float* col = W3t + (size_t)r * DH;
            float s0 = 0.f, s1 = 0.f;
#pragma unroll
            for (int j = 0; j < DH; j += 2) {
                s0 += hsh[wid][j] * col[j];
                s1 += hsh[wid][j + 1] * col[j + 1];
            }
            int slot = (r < 31) ? r : ((r < 85) ? r + 1 : r + 3);
            trow[slot] = (s0 + s1) * 0.125f;
        }
    }
    if (lane == 0) { trow[31] = 0.f; trow[86] = 0.f; trow[87] = 0.f; trow[138] = 0.f; trow[139] = 0.f; }
}

// ================= split TP kernels: shared prologue + per-pass bodies =================
#define RC2 0.7071067811865476f
#define RC6 0.40824829046386302f

#define PROLOGUE                                                            \
    int e = blockIdx.x * 256 + threadIdx.x;                                 \
    if (e >= NE) return;                                                    \
    int is = snd[e], ir = rcv[e];                                           \
    const float* xs = cur + (size_t)is * FEAT;                              \
    float4 qs = ((const float4*)xs)[4];                                     \
    float4 qr = ((const float4*)(cur + (size_t)ir * FEAT))[4];              \
    float rx = qs.x - qr.x, ry = qs.y - qr.y, rz = qs.z - qr.z;             \
    float d = sqrtf(rx * rx + ry * ry + rz * rz);                           \
    float dsafe = fmaxf(d, 1e-9f);                                          \
    float rinv = 1.f / dsafe;                                               \
    float nx = rx * rinv, ny = ry * rinv, nz = rz * rinv;                   \
    float a1[3] = {1.7320508075688772f * nx, 1.7320508075688772f * ny, 1.7320508075688772f * nz}; \
    float a2[5] = {3.872983346207417f * nx * ny,                            \
                   3.872983346207417f * ny * nz,                            \
                   1.118033988749895f * (3.f * nz * nz - 1.f),              \
                   3.872983346207417f * nx * nz,                            \
                   1.9364916731037085f * (nx * nx - ny * ny)};              \
    float pos = dsafe * rcpf(DCV + dsafe) * (float)ENT;                     \
    int idx = (int)pos;                                                     \
    if (idx > ENT - 2) idx = ENT - 2;                                       \
    float fr = pos - (float)idx;                                            \
    const float4* r0 = table4 + (size_t)idx * ROW4;                         \
    const float4* r1 = r0 + ROW4;

#define LERP4(dst, g)                                                       \
    {                                                                       \
        float4 _a = r0[g], _b = r1[g];                                      \
        dst[0] = _a.x + fr * (_b.x - _a.x);                                 \
        dst[1] = _a.y + fr * (_b.y - _a.y);                                 \
        dst[2] = _a.z + fr * (_b.z - _a.z);                                 \
        dst[3] = _a.w + fr * (_b.w - _a.w);                                 \
    }
#define BUILD_MS(ms)                                                        \
    {                                                                       \
        float sb[16];                                                       \
        const float4* p4 = (const float4*)xs;                               \
        _Pragma("unroll")                                                   \
        for (int i = 0; i < 4; i++) {                                       \
            float4 q = p4[i];                                               \
            sb[4 * i] = q.x; sb[4 * i + 1] = q.y; sb[4 * i + 2] = q.z; sb[4 * i + 3] = q.w; \
        }                                                                   \
        _Pragma("unroll")                                                   \
        for (int o = 0; o < 16; o++) ms[o] = 0.f;                           \
        _Pragma("unroll")                                                   \
        for (int i = 0; i < 16; i++) {                                      \
            float si = sb[i];                                               \
            _Pragma("unroll")                                               \
            for (int o = 0; o < 16; o++) ms[o] += si * Wls[i * 16 + o];     \
        }                                                                   \
        _Pragma("unroll")                                                   \
        for (int o = 0; o < 16; o++) ms[o] *= 0.25f;                        \
    }
#define BUILD_MV(mv)                                                        \
    {                                                                       \
        float vb[24];                                                       \
        const float4* p4 = (const float4*)(xs + 16);                        \
        _Pragma("unroll")                                                   \
        for (int i = 0; i < 6; i++) {                                       \
            float4 q = p4[i];                                               \
            vb[4 * i] = q.x; vb[4 * i + 1] = q.y; vb[4 * i + 2] = q.z; vb[4 * i + 3] = q.w; \
        }                                                                   \
        _Pragma("unroll")                                                   \
        for (int o = 0; o < 8; o++) { mv[o][0] = 0.f; mv[o][1] = 0.f; mv[o][2] = 0.f; } \
        _Pragma("unroll")                                                   \
        for (int i = 0; i < 8; i++)                                         \
            _Pragma("unroll")                                               \
            for (int o = 0; o < 8; o++) {                                   \
                float w = Wlv[i * 8 + o];                                   \
                mv[o][0] += vb[i * 3 + 0] * w;                              \
                mv[o][1] += vb[i * 3 + 1] * w;                              \
                mv[o][2] += vb[i * 3 + 2] * w;                              \
            }                                                               \
        _Pragma("unroll")                                                   \
        for (int o = 0; o < 8; o++) {                                       \
            mv[o][0] *= 0.3535533905932738f; mv[o][1] *= 0.3535533905932738f; mv[o][2] *= 0.3535533905932738f; \
        }                                                                   \
        mv[8][0] = a1[0]; mv[8][1] = a1[1]; mv[8][2] = a1[2];               \
    }
#define BUILD_MT(mt)                                                        \
    {                                                                       \
        float tb[20];                                                       \
        const float4* p4 = (const float4*)(xs + 40);                        \
        _Pragma("unroll")                                                   \
        for (int i = 0; i < 5; i++) {                                       \
            float4 q = p4[i];                                               \
            tb[4 * i] = q.x; tb[4 * i + 1] = q.y; tb[4 * i + 2] = q.z; tb[4 * i + 3] = q.w; \
        }                                                                   \
        _Pragma("unroll")                                                   \
        for (int o = 0; o < 4; o++)                                         \
            _Pragma("unroll")                                               \
            for (int c = 0; c < 5; c++) mt[o][c] = 0.f;                     \
        _Pragma("unroll")                                                   \
        for (int i = 0; i < 4; i++)                                         \
            _Pragma("unroll")                                               \
            for (int o = 0; o < 4; o++) {                                   \
                float w = Wlt[i * 4 + o];                                   \
                _Pragma("unroll")                                           \
                for (int c = 0; c < 5; c++) mt[o][c] += tb[i * 5 + c] * w;  \
            }                                                               \
        _Pragma("unroll")                                                   \
        for (int o = 0; o < 4; o++)                                         \
            _Pragma("unroll")                                               \
            for (int c = 0; c < 5; c++) mt[o][c] *= 0.5f;                   \
        _Pragma("unroll")                                                   \
        for (int c = 0; c < 5; c++) mt[4][c] = a2[c];                       \
    }
#define BUILD_A                                                             \
    float A00 = -RC6 * a2[2] + RC2 * a2[4];                                 \
    float A01 = RC2 * a2[0];                                                \
    float A02 = RC2 * a2[3];                                                \
    float A11 = -RC6 * a2[2] - RC2 * a2[4];                                 \
    float A12 = RC2 * a2[1];                                                \
    float A22 = 2.f * RC6 * a2[2];

// ===== Pass S kernel =====
__global__ __launch_bounds__(256) void tpS_kernel(
    const float* __restrict__ cur, const int* __restrict__ snd, const int* __restrict__ rcv,
    const float* __restrict__ Wls, const float* __restrict__ Wlv, const float* __restrict__ Wlt,
    const float* __restrict__ Wms, const float4* __restrict__ table4,
    float* __restrict__ msgS)
{
    PROLOGUE
    float wl[32];
#pragma unroll
    for (int g = 0; g < 8; g++) LERP4((&wl[4 * g]), g);
    float aS[28];
#pragma unroll
    for (int o = 0; o < 28; o++) aS[o] = 0.f;
    {
        float ms[16];
        BUILD_MS(ms);
#pragma unroll
        for (int i = 0; i < 17; i++) {
            float sm = ((i < 16) ? ms[i] : 1.f) * wl[i];
#pragma unroll
            for (int o = 0; o < 28; o++) aS[o] += sm * Wms[i * 28 + o];
        }
    }
    {
        float db[8];
        const float4* p4 = (const float4*)(xs + 16);
        float vb[24];
#pragma unroll
        for (int i = 0; i < 6; i++) {
            float4 q = p4[i];
            vb[4 * i] = q.x; vb[4 * i + 1] = q.y; vb[4 * i + 2] = q.z; vb[4 * i + 3] = q.w;
        }
#pragma unroll
        for (int i = 0; i < 8; i++)
            db[i] = vb[i * 3] * a1[0] + vb[i * 3 + 1] * a1[1] + vb[i * 3 + 2] * a1[2];
#pragma unroll
        for (int mm = 0; mm < 9; mm++) {
            float sval;
            if (mm < 8) {
                sval = 0.f;
#pragma unroll
                for (int i = 0; i < 8; i++) sval += db[i] * Wlv[i * 8 + mm];
                sval *= 0.3535533905932738f;
            } else {
                sval = a1[0] * a1[0] + a1[1] * a1[1] + a1[2] * a1[2];
            }
            float sm = sval * wl[17 + mm];
#pragma unroll
            for (int o = 0; o < 28; o++) aS[o] += sm * Wms[(17 + mm) * 28 + o];
        }
    }
    {
        float dt[4];
        const float4* p4 = (const float4*)(xs + 40);
        float tb[20];
#pragma unroll
        for (int i = 0; i < 5; i++) {
            float4 q = p4[i];
            tb[4 * i] = q.x; tb[4 * i + 1] = q.y; tb[4 * i + 2] = q.z; tb[4 * i + 3] = q.w;
        }
#pragma unroll
        for (int i = 0; i < 4; i++)
            dt[i] = tb[i * 5] * a2[0] + tb[i * 5 + 1] * a2[1] + tb[i * 5 + 2] * a2[2] +
                    tb[i * 5 + 3] * a2[3] + tb[i * 5 + 4] * a2[4];
#pragma unroll
        for (int mm = 0; mm < 5; mm++) {
            float sval;
            if (mm < 4) {
                sval = 0.f;
#pragma unroll
                for (int i = 0; i < 4; i++) sval += dt[i] * Wlt[i * 4 + mm];
                sval *= 0.5f;
            } else {
                sval = a2[0] * a2[0] + a2[1] * a2[1] + a2[2] * a2[2] + a2[3] * a2[3] + a2[4] * a2[4];
            }
            float sm = sval * wl[26 + mm];
#pragma unroll
            for (int o = 0; o < 28; o++) aS[o] += sm * Wms[(26 + mm) * 28 + o];
        }
    }
    const float kS = 0.17960530202677491f;
    float4* mrow = (float4*)(msgS + (size_t)e * 28);
#pragma unroll
    for (int i = 0; i < 7; i++) {
        float4 q;
        q.x = aS[4 * i] * kS; q.y = aS[4 * i + 1] * kS;
        q.z = aS[4 * i + 2] * kS; q.w = aS[4 * i + 3] * kS;
        mrow[i] = q;
    }
}

// ===== Pass V kernel =====
__global__ __launch_bounds__(256) void tpV_kernel(
    const float* __restrict__ cur, const int* __restrict__ snd, const int* __restrict__ rcv,
    const float* __restrict__ Wls, const float* __restrict__ Wlv, const float* __restrict__ Wlt,
    const float* __restrict__ Wmv, const float4* __restrict__ table4,
    float* __restrict__ msgV)
{
    PROLOGUE
    BUILD_A
    float aV[24];
#pragma unroll
    for (int o = 0; o < 24; o++) aV[o] = 0.f;
#define ADDV(vx, vy, vz, wm, row)                                           \
    {                                                                       \
        float _x = (vx) * (wm), _y = (vy) * (wm), _z = (vz) * (wm);         \
        _Pragma("unroll")                                                   \
        for (int o = 0; o < 8; o++) {                                       \
            float w = Wmv[(row) * 8 + o];                                   \
            aV[o * 3] += _x * w; aV[o * 3 + 1] += _y * w; aV[o * 3 + 2] += _z * w; \
        }                                                                   \
    }
    float mv[9][3];
    {
        float wl[28];
#pragma unroll
        for (int g = 0; g < 7; g++) LERP4((&wl[4 * g]), 8 + g);
        {
            float ms[16];
            BUILD_MS(ms);
#pragma unroll
            for (int i = 0; i < 17; i++) {
                float mi = (i < 16) ? ms[i] : 1.f;
                ADDV(mi * a1[0], mi * a1[1], mi * a1[2], wl[i], i);
            }
        }
        BUILD_MV(mv);
#pragma unroll
        for (int mm = 0; mm < 9; mm++) {
            ADDV(mv[mm][0], mv[mm][1], mv[mm][2], wl[17 + mm], 17 + mm);
        }
    }
    {
        float wl[32];
#pragma unroll
        for (int g = 0; g < 8; g++) LERP4((&wl[4 * g]), 14 + g);
#pragma unroll
        for (int mm = 0; mm < 9; mm++) {
            float v0 = mv[mm][0], v1 = mv[mm][1], v2 = mv[mm][2];
            ADDV(v1 * a1[2] - v2 * a1[1], v2 * a1[0] - v0 * a1[2], v0 * a1[1] - v1 * a1[0],
                 wl[2 + mm], 26 + mm);
            ADDV(A00 * v0 + A01 * v1 + A02 * v2, A01 * v0 + A11 * v1 + A12 * v2,
                 A02 * v0 + A12 * v1 + A22 * v2, wl[11 + mm], 35 + mm);
        }
        float mt[5][5];
        BUILD_MT(mt);
#pragma unroll
        for (int mm = 0; mm < 5; mm++) {
            float t0 = mt[mm][0], t1 = mt[mm][1], t2 = mt[mm][2], t3 = mt[mm][3], t4 = mt[mm][4];
            float T00 = -RC6 * t2 + RC2 * t4, T01 = RC2 * t0, T02 = RC2 * t3;
            float T11 = -RC6 * t2 - RC2 * t4, T12 = RC2 * t1, T22 = 2.f * RC6 * t2;
            ADDV(T00 * a1[0] + T01 * a1[1] + T02 * a1[2],
                 T01 * a1[0] + T11 * a1[1] + T12 * a1[2],
                 T02 * a1[0] + T12 * a1[1] + T22 * a1[2], wl[20 + mm], 44 + mm);
            float P01 = T00 * A01 + T01 * A11 + T02 * A12;
            float P02 = T00 * A02 + T01 * A12 + T02 * A22;
            float P10 = T01 * A00 + T11 * A01 + T12 * A02;
            float P12 = T01 * A02 + T11 * A12 + T12 * A22;
            float P20 = T02 * A00 + T12 * A01 + T22 * A02;
            float P21 = T02 * A01 + T12 * A11 + T22 * A12;
            ADDV(P12 - P21, P20 - P02, P01 - P10, wl[25 + mm], 49 + mm);
        }
    }
#undef ADDV
    const float kV = 0.13608276348795434f;
    float4* mrow = (float4*)(msgV + (size_t)e * 24);
#pragma unroll
    for (int i = 0; i < 6; i++) {
        float4 q;
        q.x = aV[4 * i] * kV; q.y = aV[4 * i + 1] * kV;
        q.z = aV[4 * i + 2] * kV; q.w = aV[4 * i + 3] * kV;
        mrow[i] = q;
    }
}

// ===== Pass T kernel =====
__global__ __launch_bounds__(256) void tpT_kernel(
    const float* __restrict__ cur, const int* __restrict__ snd, const int* __restrict__ rcv,
    const float* __restrict__ Wls, const float* __restrict__ Wlv, const float* __restrict__ Wlt,
    const float* __restrict__ Wmt, const float4* __restrict__ table4,
    float* __restrict__ msgT)
{
    PROLOGUE
    BUILD_A
    float aT[20];
#pragma unroll
    for (int o = 0; o < 20; o++) aT[o] = 0.f;
#define ADDT(u0, u1, u2, u3, u4, wm, row)                                   \
    {                                                                       \
        float _0 = (u0) * (wm), _1 = (u1) * (wm), _2 = (u2) * (wm),         \
              _3 = (u3) * (wm), _4 = (u4) * (wm);                           \
        _Pragma("unroll")                                                   \
        for (int o = 0; o < 4; o++) {                                       \
            float w = Wmt[(row) * 4 + o];                                   \
            aT[o * 5] += _0 * w; aT[o * 5 + 1] += _1 * w;                   \
            aT[o * 5 + 2] += _2 * w; aT[o * 5 + 3] += _3 * w;               \
            aT[o * 5 + 4] += _4 * w;                                        \
        }                                                                   \
    }
#define TO5T(M00, M01, M02, M10, M11, M12, M20, M21, M22, wm, row)          \
    ADDT(RC2 * ((M01) + (M10)), RC2 * ((M12) + (M21)),                      \
         RC6 * (-(M00) - (M11) + 2.f * (M22)),                             \
         RC2 * ((M02) + (M20)), RC2 * ((M00) - (M11)), wm, row)
    {
        float wl[20];
#pragma unroll
        for (int g = 0; g < 5; g++) LERP4((&wl[4 * g]), 22 + g);
        float ms[16];
        BUILD_MS(ms);
#pragma unroll
        for (int i = 0; i < 17; i++) {
            float mi = (i < 16) ? ms[i] : 1.f;
            ADDT(mi * a2[0], mi * a2[1], mi * a2[2], mi * a2[3], mi * a2[4],
                 wl[i], i);
        }
    }
    {
        float wl[20];
#pragma unroll
        for (int g = 0; g < 5; g++) LERP4((&wl[4 * g]), 26 + g);
        float mv[9][3];
        BUILD_MV(mv);
#pragma unroll
        for (int mm = 0; mm < 9; mm++) {
            float v0 = mv[mm][0], v1 = mv[mm][1], v2 = mv[mm][2];
            TO5T(v0 * a1[0], v0 * a1[1], v0 * a1[2],
                 v1 * a1[0], v1 * a1[1], v1 * a1[2],
                 v2 * a1[0], v2 * a1[1], v2 * a1[2],
                 wl[1 + mm], 17 + mm);
            float C200 = v1 * A02 - v2 * A01, C210 = v2 * A00 - v0 * A02, C220 = v0 * A01 - v1 * A00;
            float C201 = v1 * A12 - v2 * A11, C211 = v2 * A01 - v0 * A12, C221 = v0 * A11 - v1 * A01;
            float C202 = v1 * A22 - v2 * A12, C212 = v2 * A02 - v0 * A22, C222 = v0 * A12 - v1 * A02;
            TO5T(C200, C201, C202, C210, C211, C212, C220, C221, C222,
                 wl[10 + mm], 26 + mm);
        }
    }
    {
        float wl[20];
#pragma unroll
        for (int g = 0; g < 5; g++) LERP4((&wl[4 * g]), 30 + g);
        float mt[5][5];
        BUILD_MT(mt);
#pragma unroll
        for (int mm = 0; mm < 5; mm++) {
            float t0 = mt[mm][0], t1 = mt[mm][1], t2 = mt[mm][2], t3 = mt[mm][3], t4 = mt[mm][4];
            ADDT(t0, t1, t2, t3, t4, wl[3 + mm], 35 + mm);
            float T00 = -RC6 * t2 + RC2 * t4, T01 = RC2 * t0, T02 = RC2 * t3;
            float T11 = -RC6 * t2 - RC2 * t4, T12 = RC2 * t1, T22 = 2.f * RC6 * t2;
            float u0 = a1[0], u1 = a1[1], u2 = a1[2];
            float C300 = u1 * T02 - u2 * T01, C310 = u2 * T00 - u0 * T02, C320 = u0 * T01 - u1 * T00;
            float C301 = u1 * T12 - u2 * T11, C311 = u2 * T01 - u0 * T12, C321 = u0 * T11 - u1 * T01;
            float C302 = u1 * T22 - u2 * T12, C312 = u2 * T02 - u0 * T22, C322 = u0 * T12 - u1 * T02;
            TO5T(C300, C301, C302, C310, C311, C312, C320, C321, C322,
                 wl[8 + mm], 40 + mm);
            float P00 = T00 * A00 + T01 * A01 + T02 * A02;
            float P01 = T00 * A01 + T01 * A11 + T02 * A12;
            float P02 = T00 * A02 + T01 * A12 + T02 * A22;
            float P10 = T01 * A00 + T11 * A01 + T12 * A02;
            float P11 = T01 * A01 + T11 * A11 + T12 * A12;
            float P12 = T01 * A02 + T11 * A12 + T12 * A22;
            float P20 = T02 * A00 + T12 * A01 + T22 * A02;
            float P21 = T02 * A01 + T12 * A11 + T22 * A12;
            float P22 = T02 * A02 + T12 * A12 + T22 * A22;
            TO5T(P00, P01, P02, P10, P11, P12, P20, P21, P22,
                 wl[13 + mm], 45 + mm);
        }
    }
#undef TO5T
#undef ADDT
    const float kT = 0.1414213562373095f;
    float4* mrow = (float4*)(msgT + (size_t)e * 20);
#pragma unroll
    for (int i = 0; i < 5; i++) {
        float4 q;
        q.x = aT[4 * i] * kT; q.y = aT[4 * i + 1] * kT;
        q.z = aT[4 * i + 2] * kT; q.w = aT[4 * i + 3] * kT;
        mrow[i] = q;
    }
}

// ================= gather: wave per node over 3 compact msg arrays =================
__global__ __launch_bounds__(256) void gather_kernel(
    const float4* __restrict__ msgS4, const float4* __restrict__ msgV4,
    const float4* __restrict__ msgT4, const int* __restrict__ offs,
    const int* __restrict__ elist, float4* __restrict__ agg4)
{
    int wid = threadIdx.x >> 6;
    int lane = threadIdx.x & 63;
    int n = blockIdx.x * 4 + wid;
    if (n >= NN) return;
    int sub = lane / 18;
    int q = lane - sub * 18;
    const float4* base;
    int stride, qo;
    if (q < 7)       { base = msgS4; stride = 7; qo = q; }
    else if (q < 13) { base = msgV4; stride = 6; qo = q - 7; }
    else             { base = msgT4; stride = 5; qo = q - 13; }
    int beg = offs[n], end = offs[n + 1];
    float4 acc = {0.f, 0.f, 0.f, 0.f};
    if (sub < 3) {
        for (int j = beg + sub; j < end; j += 3) {
            int e = elist[j];
            float4 m = base[(size_t)e * stride + qo];
            acc.x += m.x; acc.y += m.y; acc.z += m.z; acc.w += m.w;
        }
    }
    float bx = __shfl(acc.x, lane + 18), by = __shfl(acc.y, lane + 18);
    float bz = __shfl(acc.z, lane + 18), bw = __shfl(acc.w, lane + 18);
    float cx = __shfl(acc.x, lane + 36), cy = __shfl(acc.y, lane + 36);
    float cz = __shfl(acc.z, lane + 36), cw = __shfl(acc.w, lane + 36);
    if (lane < 18) {
        float4 r;
        r.x = acc.x + bx + cx; r.y = acc.y + by + cy;
        r.z = acc.z + bz + cz; r.w = acc.w + bw + cw;
        agg4[(size_t)n * 18 + lane] = r;
    }
}

// ================= node update =================
__global__ __launch_bounds__(256) void node_kernel(
    const float* __restrict__ cur, const float* __restrict__ agg,
    const float* __restrict__ Wns, const float* __restrict__ Wnv, const float* __restrict__ Wnt,
    const float* __restrict__ Wps, const float* __restrict__ Wpv, const float* __restrict__ Wpt,
    float* __restrict__ dst)
{
    int n = blockIdx.x * 256 + threadIdx.x;
    if (n >= NN) return;
    const float* xn = cur + (size_t)n * FEAT;
    const float* ag = agg + (size_t)n * 72;
    const float invE = 0.0025f;

    float msv[28];
#pragma unroll
    for (int o = 0; o < 28; o++) msv[o] = ag[o] * invE;
#pragma unroll
    for (int i = 0; i < 16; i++) {
        float si = xn[i] * 0.25f;
#pragma unroll
        for (int o = 0; o < 28; o++) msv[o] += si * Wns[i * 28 + o];
    }
    float mvv[8][3];
#pragma unroll
    for (int o = 0; o < 8; o++)
#pragma unroll
        for (int c = 0; c < 3; c++) mvv[o][c] = ag[28 + o * 3 + c] * invE;
#pragma unroll
    for (int i = 0; i < 8; i++)
#pragma unroll
        for (int o = 0; o < 8; o++) {
            float w = Wnv[i * 8 + o] * 0.3535533905932738f;
#pragma unroll
            for (int c = 0; c < 3; c++) mvv[o][c] += xn[16 + i * 3 + c] * w;
        }
    float mtv[4][5];
#pragma unroll
    for (int o = 0; o < 4; o++)
#pragma unroll
        for (int c = 0; c < 5; c++) mtv[o][c] = ag[52 + o * 5 + c] * invE;
#pragma unroll
    for (int i = 0; i < 4; i++)
#pragma unroll
        for (int o = 0; o < 4; o++) {
            float w = Wnt[i * 4 + o] * 0.5f;
#pragma unroll
            for (int c = 0; c < 5; c++) mtv[o][c] += xn[40 + i * 5 + c] * w;
        }

    float g[12];
#pragma unroll
    for (int j = 0; j < 12; j++) g[j] = sigmoidf_(msv[16 + j]);
    float hs[16];
#pragma unroll
    for (int i = 0; i < 16; i++) hs[i] = geluf(msv[i]);

    float outv[60];
#pragma unroll
    for (int o = 0; o < 16; o++) outv[o] = 0.f;
#pragma unroll
    for (int i = 0; i < 16; i++) {
        float si = hs[i] * 0.25f;
#pragma unroll
        for (int o = 0; o < 16; o++) outv[o] += si * Wps[i * 16 + o];
    }
#pragma unroll
    for (int o = 0; o < 8; o++)
#pragma unroll
        for (int c = 0; c < 3; c++) outv[16 + o * 3 + c] = 0.f;
#pragma unroll
    for (int i = 0; i < 8; i++) {
        float gi = g[i];
#pragma unroll
        for (int o = 0; o < 8; o++) {
            float w = Wpv[i * 8 + o] * 0.3535533905932738f * gi;
#pragma unroll
            for (int c = 0; c < 3; c++) outv[16 + o * 3 + c] += mvv[i][c] * w;
        }
    }
#pragma unroll
    for (int o = 0; o < 4; o++)
#pragma unroll
        for (int c = 0; c < 5; c++) outv[40 + o * 5 + c] = 0.f;
#pragma unroll
    for (int i = 0; i < 4; i++) {
        float gi = g[8 + i];
#pragma unroll
        for (int o = 0; o < 4; o++) {
            float w = Wpt[i * 4 + o] * 0.5f * gi;
#pragma unroll
            for (int c = 0; c < 5; c++) outv[40 + o * 5 + c] += mtv[i][c] * w;
        }
    }

    float4* dst4 = (float4*)(dst + (size_t)n * FEAT);
#pragma unroll
    for (int i = 0; i < 15; i++) {
        float4 q;
        q.x = outv[4 * i]; q.y = outv[4 * i + 1]; q.z = outv[4 * i + 2]; q.w = outv[4 * i + 3];
        dst4[i] = q;
    }
}

// ================= host =================
static inline size_t algn(size_t o) { return (o + 63) & ~(size_t)63; }

extern "C" void kernel_launch(void* const* d_in, const int* in_sizes, int n_in,
                              void* d_out, int out_size, void* d_ws, size_t ws_size,
                              hipStream_t stream)
{
    const float* x    = (const float*)d_in[0];
    const float* Wl_s = (const float*)d_in[1];
    const float* Wl_v = (const float*)d_in[2];
    const float* Wl_t = (const float*)d_in[3];
    const float* Wr0  = (const float*)d_in[4];
    const float* Wr1  = (const float*)d_in[5];
    const float* Wr2  = (const float*)d_in[6];
    const float* Wr3  = (const float*)d_in[7];
    const float* Wm_s = (const float*)d_in[8];
    const float* Wm_v = (const float*)d_in[9];
    const float* Wm_t = (const float*)d_in[10];
    const float* Wn_s = (const float*)d_in[11];
    const float* Wn_v = (const float*)d_in[12];
    const float* Wn_t = (const float*)d_in[13];
    const float* Wp_s = (const float*)d_in[14];
    const float* Wp_v = (const float*)d_in[15];
    const float* Wp_t = (const float*)d_in[16];
    const int* snd = (const int*)d_in[17];
    const int* rcv = (const int*)d_in[18];
    float* out = (float*)d_out;

    char* ws = (char*)d_ws;
    size_t off = 0;
    float* cur    = (float*)(ws + off); off = algn(off + (size_t)NN * FEAT * 4);
    float* agg    = (float*)(ws + off); off = algn(off + (size_t)NN * 72 * 4);
    float* msgS   = (float*)(ws + off); off = algn(off + (size_t)NE * 28 * 4);
    float* msgV   = (float*)(ws + off); off = algn(off + (size_t)NE * 24 * 4);
    float* msgT   = (float*)(ws + off); off = algn(off + (size_t)NE * 20 * 4);
    int*   counts = (int*)(ws + off);   off = algn(off + (size_t)NN * 4);
    int*   offs   = (int*)(ws + off);   off = algn(off + (size_t)(NN + 1) * 4);
    int*   rank   = (int*)(ws + off);   off = algn(off + (size_t)NE * 4);
    int*   elist  = (int*)(ws + off);   off = algn(off + (size_t)NE * 4);
    float* W3t    = (float*)(ws + off); off = algn(off + (size_t)3 * NIR * DH * 4);
    float* table  = (float*)(ws + off); off = algn(off + (size_t)ENT * ROWF * 4);

    hipMemcpyAsync(cur, x, (size_t)NN * FEAT * 4, hipMemcpyDeviceToDevice, stream);
    hipMemsetAsync(counts, 0, (size_t)NN * 4, stream);
    int nb = (NE + 255) / 256;
    csr_hist<<<nb, 256, 0, stream>>>(rcv, counts, rank);
    csr_scan<<<1, 1024, 0, stream>>>(counts, offs);
    csr_fill<<<nb, 256, 0, stream>>>(rcv, offs, rank, elist);
    w3t_kernel<<<(3 * NIR * DH + 255) / 256, 256, 0, stream>>>(Wr3, W3t);

    for (int k = 0; k < 3; k++) {
        const float* W0  = Wr0 + (size_t)k * 4 * DH;
        const float* W1  = Wr1 + (size_t)k * DH * DH;
        const float* W2  = Wr2 + (size_t)k * DH * DH;
        const float* W3tk= W3t + (size_t)k * NIR * DH;
        const float* Wls = Wl_s + (size_t)k * 16 * 16;
        const float* Wlv = Wl_v + (size_t)k * 8 * 8;
        const float* Wlt = Wl_t + (size_t)k * 4 * 4;
        const float* Wms = Wm_s + (size_t)k * SC * 28;
        const float* Wmv = Wm_v + (size_t)k * VC * 8;
        const float* Wmt = Wm_t + (size_t)k * TC * 4;
        const float* Wns = Wn_s + (size_t)k * 16 * 28;
        const float* Wnv = Wn_v + (size_t)k * 8 * 8;
        const float* Wnt = Wn_t + (size_t)k * 4 * 4;
        const float* Wps = Wp_s + (size_t)k * 16 * 16;
        const float* Wpv = Wp_v + (size_t)k * 8 * 8;
        const float* Wpt = Wp_t + (size_t)k * 4 * 4;

        table_kernel<<<ENT / 4, 256, 0, stream>>>(W0, W1, W2, W3tk, table);
        tpS_kernel<<<nb, 256, 0, stream>>>(cur, snd, rcv, Wls, Wlv, Wlt, Wms,
                                           (const float4*)table, msgS);
        tpV_kernel<<<nb, 256, 0, stream>>>(cur, snd, rcv, Wls, Wlv, Wlt, Wmv,
                                           (const float4*)table, msgV);
        tpT_kernel<<<nb, 256, 0, stream>>>(cur, snd, rcv, Wls, Wlv, Wlt, Wmt,
                                           (const float4*)table, msgT);
        gather_kernel<<<(NN + 3) / 4, 256, 0, stream>>>(
            (const float4*)msgS, (const float4*)msgV, (const float4*)msgT,
            offs, elist, (float4*)agg);
        float* dst = (k == 2) ? out : cur;
        node_kernel<<<(NN + 255) / 256, 256, 0, stream>>>(cur, agg, Wns, Wnv, Wnt,
                                                          Wps, Wpv, Wpt, dst);
    }
}

// Round 20
// 476.291 us; speedup vs baseline: 1.1084x; 1.1084x over previous
//
#include <hip/hip_runtime.h>
#include <math.h>

#define DEV __device__ __forceinline__

#define NN 10000
#define NE 160000
#define DH 64
#define SC 31
#define VC 54
#define TC 50
#define NIR 135
#define FEAT 60
#define ENT 4096     // radial table entries
#define ROWF 140     // table row floats: S@0(31) pad | V@32(54) pad | T@88(50) pad
#define ROW4 35      // table row float4s
#define DCV 4.0f     // rational map scale: u = d/(DCV+d)

DEV float rcpf(float x) { return __builtin_amdgcn_rcpf(x); }

DEV float geluf(float x) {
    float u = 0.7978845608028654f * (x + 0.044715f * x * x * x);
    u = fminf(fmaxf(u, -9.f), 9.f);
    float e = __expf(2.f * u);
    float th = (e - 1.f) * rcpf(e + 1.f);
    return 0.5f * x * (1.f + th);
}
DEV float sigmoidf_(float x) { return rcpf(1.f + __expf(-x)); }

// ================= CSR build (once per launch) =================
__global__ __launch_bounds__(256) void csr_hist(const int* __restrict__ rcv,
                                                int* __restrict__ counts,
                                                int* __restrict__ rank) {
    int e = blockIdx.x * 256 + threadIdx.x;
    if (e >= NE) return;
    rank[e] = atomicAdd(&counts[rcv[e]], 1);
}

__global__ __launch_bounds__(1024) void csr_scan(const int* __restrict__ counts,
                                                 int* __restrict__ offs) {
    __shared__ int buf[1024];
    __shared__ int carry_s;
    if (threadIdx.x == 0) carry_s = 0;
    __syncthreads();
    for (int base = 0; base < 10240; base += 1024) {
        int i = base + threadIdx.x;
        int v = (i < NN) ? counts[i] : 0;
        buf[threadIdx.x] = v;
        __syncthreads();
        for (int off = 1; off < 1024; off <<= 1) {
            int t = (threadIdx.x >= off) ? buf[threadIdx.x - off] : 0;
            __syncthreads();
            buf[threadIdx.x] += t;
            __syncthreads();
        }
        int cbase = carry_s;
        int incl = buf[threadIdx.x];
        if (i < NN) offs[i] = cbase + incl - v;
        int total = buf[1023];
        __syncthreads();
        if (threadIdx.x == 0) carry_s = cbase + total;
        __syncthreads();
    }
    if (threadIdx.x == 0) offs[NN] = carry_s;
}

__global__ __launch_bounds__(256) void csr_fill(const int* __restrict__ rcv,
                                                const int* __restrict__ offs,
                                                const int* __restrict__ rank,
                                                int* __restrict__ elist) {
    int e = blockIdx.x * 256 + threadIdx.x;
    if (e >= NE) return;
    elist[offs[rcv[e]] + rank[e]] = e;
}

// ================= W3 transpose (once per launch) =================
__global__ __launch_bounds__(256) void w3t_kernel(const float* __restrict__ Wr3,
                                                  float* __restrict__ W3t) {
    int t = blockIdx.x * 256 + threadIdx.x;
    if (t >= 3 * NIR * DH) return;
    int k = t / (NIR * DH), r = t % (NIR * DH);
    int i = r / DH, j = r % DH;
    W3t[t] = Wr3[k * DH * NIR + j * NIR + i];
}

// ================= table: radial MLP on rational grid, ONE WAVE PER ENTRY =================
__global__ __launch_bounds__(256) void table_kernel(
    const float* __restrict__ W0, const float* __restrict__ W1,
    const float* __restrict__ W2, const float* __restrict__ W3t,
    float* __restrict__ table)
{
    __shared__ float hsh[4][DH];
    int wid = threadIdx.x >> 6;
    int lane = threadIdx.x & 63;
    int i = blockIdx.x * 4 + wid;

    float u = (float)i / (float)ENT;
    float ds = fmaxf(DCV * u * rcpf(1.f - u), 1e-9f);
    float rinv = 1.f / ds;
    float R4[4];
#pragma unroll
    for (int b = 0; b < 4; b++)
        R4[b] = sinf((float)(b + 1) * 1.5707963267948966f * ds) * rinv;

    float h = geluf((R4[0] * W0[lane] + R4[1] * W0[DH + lane] +
                     R4[2] * W0[2 * DH + lane] + R4[3] * W0[3 * DH + lane]) * 0.5f);
    hsh[wid][lane] = h;
    __syncthreads();

    {
        float acc = 0.f;
#pragma unroll
        for (int j = 0; j < DH; j++) acc += hsh[wid][j] * W1[j * DH + lane];
        h = geluf(acc * 0.125f);
    }
    __syncthreads();
    hsh[wid][lane] = h;
    __syncthreads();

    {
        float acc = 0.f;
#pragma unroll
        for (int j = 0; j < DH; j++) acc += hsh[wid][j] * W2[j * DH + lane];
        h = geluf(acc * 0.125f);
    }
    __syncthreads();
    hsh[wid][lane] = h;
    __syncthreads();

    float* trow = table + (size_t)i * ROWF;
#pragma unroll
    for (int rb = 0; rb < 3; rb++) {
        int r = rb * 64 + lane;
        if (r < NIR) {
            const float* col = W3t + (size_t)r * DH;
            float s0 = 0.f, s1 = 0.f;
#pragma unroll
            for (int j = 0; j < DH; j += 2) {
                s0 += hsh[wid][j] * col[j];
                s1 += hsh[wid][j + 1] * col[j + 1];
            }
            int slot = (r < 31) ? r : ((r < 85) ? r + 1 : r + 3);
            trow[slot] = (s0 + s1) * 0.125f;
        }
    }
    if (lane == 0) { trow[31] = 0.f; trow[86] = 0.f; trow[87] = 0.f; trow[138] = 0.f; trow[139] = 0.f; }
}

// ================= tp3: fat-grid 3-pass TP, inline lerp (rational map) =================
#define RC2 0.7071067811865476f
#define RC6 0.40824829046386302f

__global__ __launch_bounds__(256) void tp3_kernel(
    const float* __restrict__ cur, const int* __restrict__ snd, const int* __restrict__ rcv,
    const float* __restrict__ Wls, const float* __restrict__ Wlv, const float* __restrict__ Wlt,
    const float* __restrict__ Wms, const float* __restrict__ Wmv, const float* __restrict__ Wmt,
    const float4* __restrict__ table4,
    float* __restrict__ msgS, float* __restrict__ msgV, float* __restrict__ msgT, int nbp)
{
    int pass = blockIdx.x / nbp;
    int e = (blockIdx.x - pass * nbp) * 256 + threadIdx.x;
    if (e >= NE) return;
    int is = snd[e], ir = rcv[e];
    const float* xs = cur + (size_t)is * FEAT;

    float4 qs = ((const float4*)xs)[4];
    float4 qr = ((const float4*)(cur + (size_t)ir * FEAT))[4];
    float rx = qs.x - qr.x, ry = qs.y - qr.y, rz = qs.z - qr.z;
    float d = sqrtf(rx * rx + ry * ry + rz * rz);
    float dsafe = fmaxf(d, 1e-9f);
    float rinv = 1.f / dsafe;
    float nx = rx * rinv, ny = ry * rinv, nz = rz * rinv;
    float a1[3] = {1.7320508075688772f * nx, 1.7320508075688772f * ny, 1.7320508075688772f * nz};
    float a2[5] = {3.872983346207417f * nx * ny,
                   3.872983346207417f * ny * nz,
                   1.118033988749895f * (3.f * nz * nz - 1.f),
                   3.872983346207417f * nx * nz,
                   1.9364916731037085f * (nx * nx - ny * ny)};

    float pos = dsafe * rcpf(DCV + dsafe) * (float)ENT;
    int idx = (int)pos;
    if (idx > ENT - 2) idx = ENT - 2;
    float fr = pos - (float)idx;
    const float4* r0 = table4 + (size_t)idx * ROW4;
    const float4* r1 = r0 + ROW4;

#define LERP4(dst, g)                                                       \
    {                                                                       \
        float4 _a = r0[g], _b = r1[g];                                      \
        dst[0] = _a.x + fr * (_b.x - _a.x);                                 \
        dst[1] = _a.y + fr * (_b.y - _a.y);                                 \
        dst[2] = _a.z + fr * (_b.z - _a.z);                                 \
        dst[3] = _a.w + fr * (_b.w - _a.w);                                 \
    }
#define BUILD_MS(ms)                                                        \
    {                                                                       \
        float sb[16];                                                       \
        const float4* p4 = (const float4*)xs;                               \
        _Pragma("unroll")                                                   \
        for (int i = 0; i < 4; i++) {                                       \
            float4 q = p4[i];                                               \
            sb[4 * i] = q.x; sb[4 * i + 1] = q.y; sb[4 * i + 2] = q.z; sb[4 * i + 3] = q.w; \
        }                                                                   \
        _Pragma("unroll")                                                   \
        for (int o = 0; o < 16; o++) ms[o] = 0.f;                           \
        _Pragma("unroll")                                                   \
        for (int i = 0; i < 16; i++) {                                      \
            float si = sb[i];                                               \
            _Pragma("unroll")                                               \
            for (int o = 0; o < 16; o++) ms[o] += si * Wls[i * 16 + o];     \
        }                                                                   \
        _Pragma("unroll")                                                   \
        for (int o = 0; o < 16; o++) ms[o] *= 0.25f;                        \
    }
#define BUILD_MV(mv)                                                        \
    {                                                                       \
        float vb[24];                                                       \
        const float4* p4 = (const float4*)(xs + 16);                        \
        _Pragma("unroll")                                                   \
        for (int i = 0; i < 6; i++) {                                       \
            float4 q = p4[i];                                               \
            vb[4 * i] = q.x; vb[4 * i + 1] = q.y; vb[4 * i + 2] = q.z; vb[4 * i + 3] = q.w; \
        }                                                                   \
        _Pragma("unroll")                                                   \
        for (int o = 0; o < 8; o++) { mv[o][0] = 0.f; mv[o][1] = 0.f; mv[o][2] = 0.f; } \
        _Pragma("unroll")                                                   \
        for (int i = 0; i < 8; i++)                                         \
            _Pragma("unroll")                                               \
            for (int o = 0; o < 8; o++) {                                   \
                float w = Wlv[i * 8 + o];                                   \
                mv[o][0] += vb[i * 3 + 0] * w;                              \
                mv[o][1] += vb[i * 3 + 1] * w;                              \
                mv[o][2] += vb[i * 3 + 2] * w;                              \
            }                                                               \
        _Pragma("unroll")                                                   \
        for (int o = 0; o < 8; o++) {                                       \
            mv[o][0] *= 0.3535533905932738f; mv[o][1] *= 0.3535533905932738f; mv[o][2] *= 0.3535533905932738f; \
        }                                                                   \
        mv[8][0] = a1[0]; mv[8][1] = a1[1]; mv[8][2] = a1[2];               \
    }
#define BUILD_MT(mt)                                                        \
    {                                                                       \
        float tb[20];                                                       \
        const float4* p4 = (const float4*)(xs + 40);                        \
        _Pragma("unroll")                                                   \
        for (int i = 0; i < 5; i++) {                                       \
            float4 q = p4[i];                                               \
            tb[4 * i] = q.x; tb[4 * i + 1] = q.y; tb[4 * i + 2] = q.z; tb[4 * i + 3] = q.w; \
        }                                                                   \
        _Pragma("unroll")                                                   \
        for (int o = 0; o < 4; o++)                                         \
            _Pragma("unroll")                                               \
            for (int c = 0; c < 5; c++) mt[o][c] = 0.f;                     \
        _Pragma("unroll")                                                   \
        for (int i = 0; i < 4; i++)                                         \
            _Pragma("unroll")                                               \
            for (int o = 0; o < 4; o++) {                                   \
                float w = Wlt[i * 4 + o];                                   \
                _Pragma("unroll")                                           \
                for (int c = 0; c < 5; c++) mt[o][c] += tb[i * 5 + c] * w;  \
            }                                                               \
        _Pragma("unroll")                                                   \
        for (int o = 0; o < 4; o++)                                         \
            _Pragma("unroll")                                               \
            for (int c = 0; c < 5; c++) mt[o][c] *= 0.5f;                   \
        _Pragma("unroll")                                                   \
        for (int c = 0; c < 5; c++) mt[4][c] = a2[c];                       \
    }

    if (pass == 0) {
        // ===== Pass S =====
        float wl[32];
#pragma unroll
        for (int g = 0; g < 8; g++) LERP4((&wl[4 * g]), g);
        float aS[28];
#pragma unroll
        for (int o = 0; o < 28; o++) aS[o] = 0.f;
        {
            float ms[16];
            BUILD_MS(ms);
#pragma unroll
            for (int i = 0; i < 17; i++) {
                float sm = ((i < 16) ? ms[i] : 1.f) * wl[i];
#pragma unroll
                for (int o = 0; o < 28; o++) aS[o] += sm * Wms[i * 28 + o];
            }
        }
        {
            float db[8];
            const float4* p4 = (const float4*)(xs + 16);
            float vb[24];
#pragma unroll
            for (int i = 0; i < 6; i++) {
                float4 q = p4[i];
                vb[4 * i] = q.x; vb[4 * i + 1] = q.y; vb[4 * i + 2] = q.z; vb[4 * i + 3] = q.w;
            }
#pragma unroll
            for (int i = 0; i < 8; i++)
                db[i] = vb[i * 3] * a1[0] + vb[i * 3 + 1] * a1[1] + vb[i * 3 + 2] * a1[2];
#pragma unroll
            for (int mm = 0; mm < 9; mm++) {
                float sval;
                if (mm < 8) {
                    sval = 0.f;
#pragma unroll
                    for (int i = 0; i < 8; i++) sval += db[i] * Wlv[i * 8 + mm];
                    sval *= 0.3535533905932738f;
                } else {
                    sval = a1[0] * a1[0] + a1[1] * a1[1] + a1[2] * a1[2];
                }
                float sm = sval * wl[17 + mm];
#pragma unroll
                for (int o = 0; o < 28; o++) aS[o] += sm * Wms[(17 + mm) * 28 + o];
            }
        }
        {
            float dt[4];
            const float4* p4 = (const float4*)(xs + 40);
            float tb[20];
#pragma unroll
            for (int i = 0; i < 5; i++) {
                float4 q = p4[i];
                tb[4 * i] = q.x; tb[4 * i + 1] = q.y; tb[4 * i + 2] = q.z; tb[4 * i + 3] = q.w;
            }
#pragma unroll
            for (int i = 0; i < 4; i++)
                dt[i] = tb[i * 5] * a2[0] + tb[i * 5 + 1] * a2[1] + tb[i * 5 + 2] * a2[2] +
                        tb[i * 5 + 3] * a2[3] + tb[i * 5 + 4] * a2[4];
#pragma unroll
            for (int mm = 0; mm < 5; mm++) {
                float sval;
                if (mm < 4) {
                    sval = 0.f;
#pragma unroll
                    for (int i = 0; i < 4; i++) sval += dt[i] * Wlt[i * 4 + mm];
                    sval *= 0.5f;
                } else {
                    sval = a2[0] * a2[0] + a2[1] * a2[1] + a2[2] * a2[2] + a2[3] * a2[3] + a2[4] * a2[4];
                }
                float sm = sval * wl[26 + mm];
#pragma unroll
                for (int o = 0; o < 28; o++) aS[o] += sm * Wms[(26 + mm) * 28 + o];
            }
        }
        const float kS = 0.17960530202677491f;
        float4* mrow = (float4*)(msgS + (size_t)e * 28);
#pragma unroll
        for (int i = 0; i < 7; i++) {
            float4 q;
            q.x = aS[4 * i] * kS; q.y = aS[4 * i + 1] * kS;
            q.z = aS[4 * i + 2] * kS; q.w = aS[4 * i + 3] * kS;
            mrow[i] = q;
        }
        return;
    }

    float A00 = -RC6 * a2[2] + RC2 * a2[4];
    float A01 = RC2 * a2[0];
    float A02 = RC2 * a2[3];
    float A11 = -RC6 * a2[2] - RC2 * a2[4];
    float A12 = RC2 * a2[1];
    float A22 = 2.f * RC6 * a2[2];

    if (pass == 1) {
        // ===== Pass V: deferred sources =====
        float aV[24];
#pragma unroll
        for (int o = 0; o < 24; o++) aV[o] = 0.f;
#define ADDV(vx, vy, vz, wm, row)                                           \
        {                                                                   \
            float _x = (vx) * (wm), _y = (vy) * (wm), _z = (vz) * (wm);     \
            _Pragma("unroll")                                               \
            for (int o = 0; o < 8; o++) {                                   \
                float w = Wmv[(row) * 8 + o];                               \
                aV[o * 3] += _x * w; aV[o * 3 + 1] += _y * w; aV[o * 3 + 2] += _z * w; \
            }                                                               \
        }
        float mv[9][3];
        {
            float wl[28];
#pragma unroll
            for (int g = 0; g < 7; g++) LERP4((&wl[4 * g]), 8 + g);
            {
                float ms[16];
                BUILD_MS(ms);
#pragma unroll
                for (int i = 0; i < 17; i++) {
                    float mi = (i < 16) ? ms[i] : 1.f;
                    ADDV(mi * a1[0], mi * a1[1], mi * a1[2], wl[i], i);
                }
            }
            BUILD_MV(mv);
#pragma unroll
            for (int mm = 0; mm < 9; mm++) {
                ADDV(mv[mm][0], mv[mm][1], mv[mm][2], wl[17 + mm], 17 + mm);
            }
        }
        {
            float wl[32];
#pragma unroll
            for (int g = 0; g < 8; g++) LERP4((&wl[4 * g]), 14 + g);
#pragma unroll
            for (int mm = 0; mm < 9; mm++) {
                float v0 = mv[mm][0], v1 = mv[mm][1], v2 = mv[mm][2];
                ADDV(v1 * a1[2] - v2 * a1[1], v2 * a1[0] - v0 * a1[2], v0 * a1[1] - v1 * a1[0],
                     wl[2 + mm], 26 + mm);
                ADDV(A00 * v0 + A01 * v1 + A02 * v2, A01 * v0 + A11 * v1 + A12 * v2,
                     A02 * v0 + A12 * v1 + A22 * v2, wl[11 + mm], 35 + mm);
            }
            float mt[5][5];
            BUILD_MT(mt);
#pragma unroll
            for (int mm = 0; mm < 5; mm++) {
                float t0 = mt[mm][0], t1 = mt[mm][1], t2 = mt[mm][2], t3 = mt[mm][3], t4 = mt[mm][4];
                float T00 = -RC6 * t2 + RC2 * t4, T01 = RC2 * t0, T02 = RC2 * t3;
                float T11 = -RC6 * t2 - RC2 * t4, T12 = RC2 * t1, T22 = 2.f * RC6 * t2;
                ADDV(T00 * a1[0] + T01 * a1[1] + T02 * a1[2],
                     T01 * a1[0] + T11 * a1[1] + T12 * a1[2],
                     T02 * a1[0] + T12 * a1[1] + T22 * a1[2], wl[20 + mm], 44 + mm);
                float P01 = T00 * A01 + T01 * A11 + T02 * A12;
                float P02 = T00 * A02 + T01 * A12 + T02 * A22;
                float P10 = T01 * A00 + T11 * A01 + T12 * A02;
                float P12 = T01 * A02 + T11 * A12 + T12 * A22;
                float P20 = T02 * A00 + T12 * A01 + T22 * A02;
                float P21 = T02 * A01 + T12 * A11 + T22 * A12;
                ADDV(P12 - P21, P20 - P02, P01 - P10, wl[25 + mm], 49 + mm);
            }
        }
#undef ADDV
        const float kV = 0.13608276348795434f;
        float4* mrow = (float4*)(msgV + (size_t)e * 24);
#pragma unroll
        for (int i = 0; i < 6; i++) {
            float4 q;
            q.x = aV[4 * i] * kV; q.y = aV[4 * i + 1] * kV;
            q.z = aV[4 * i + 2] * kV; q.w = aV[4 * i + 3] * kV;
            mrow[i] = q;
        }
        return;
    }

    {
        // ===== Pass T: deferred sources =====
        float aT[20];
#pragma unroll
        for (int o = 0; o < 20; o++) aT[o] = 0.f;
#define ADDT(u0, u1, u2, u3, u4, wm, row)                                   \
        {                                                                   \
            float _0 = (u0) * (wm), _1 = (u1) * (wm), _2 = (u2) * (wm),     \
                  _3 = (u3) * (wm), _4 = (u4) * (wm);                       \
            _Pragma("unroll")                                               \
            for (int o = 0; o < 4; o++) {                                   \
                float w = Wmt[(row) * 4 + o];                               \
                aT[o * 5] += _0 * w; aT[o * 5 + 1] += _1 * w;               \
                aT[o * 5 + 2] += _2 * w; aT[o * 5 + 3] += _3 * w;           \
                aT[o * 5 + 4] += _4 * w;                                    \
            }                                                               \
        }
#define TO5T(M00, M01, M02, M10, M11, M12, M20, M21, M22, wm, row)          \
        ADDT(RC2 * ((M01) + (M10)), RC2 * ((M12) + (M21)),                  \
             RC6 * (-(M00) - (M11) + 2.f * (M22)),                         \
             RC2 * ((M02) + (M20)), RC2 * ((M00) - (M11)), wm, row)
        {
            float wl[20];
#pragma unroll
            for (int g = 0; g < 5; g++) LERP4((&wl[4 * g]), 22 + g);
            float ms[16];
            BUILD_MS(ms);
#pragma unroll
            for (int i = 0; i < 17; i++) {
                float mi = (i < 16) ? ms[i] : 1.f;
                ADDT(mi * a2[0], mi * a2[1], mi * a2[2], mi * a2[3], mi * a2[4],
                     wl[i], i);
            }
        }
        {
            float wl[20];
#pragma unroll
            for (int g = 0; g < 5; g++) LERP4((&wl[4 * g]), 26 + g);
            float mv[9][3];
            BUILD_MV(mv);
#pragma unroll
            for (int mm = 0; mm < 9; mm++) {
                float v0 = mv[mm][0], v1 = mv[mm][1], v2 = mv[mm][2];
                TO5T(v0 * a1[0], v0 * a1[1], v0 * a1[2],
                     v1 * a1[0], v1 * a1[1], v1 * a1[2],
                     v2 * a1[0], v2 * a1[1], v2 * a1[2],
                     wl[1 + mm], 17 + mm);
                float C200 = v1 * A02 - v2 * A01, C210 = v2 * A00 - v0 * A02, C220 = v0 * A01 - v1 * A00;
                float C201 = v1 * A12 - v2 * A11, C211 = v2 * A01 - v0 * A12, C221 = v0 * A11 - v1 * A01;
                float C202 = v1 * A22 - v2 * A12, C212 = v2 * A02 - v0 * A22, C222 = v0 * A12 - v1 * A02;
                TO5T(C200, C201, C202, C210, C211, C212, C220, C221, C222,
                     wl[10 + mm], 26 + mm);
            }
        }
        {
            float wl[20];
#pragma unroll
            for (int g = 0; g < 5; g++) LERP4((&wl[4 * g]), 30 + g);
            float mt[5][5];
            BUILD_MT(mt);
#pragma unroll
            for (int mm = 0; mm < 5; mm++) {
                float t0 = mt[mm][0], t1 = mt[mm][1], t2 = mt[mm][2], t3 = mt[mm][3], t4 = mt[mm][4];
                ADDT(t0, t1, t2, t3, t4, wl[3 + mm], 35 + mm);
                float T00 = -RC6 * t2 + RC2 * t4, T01 = RC2 * t0, T02 = RC2 * t3;
                float T11 = -RC6 * t2 - RC2 * t4, T12 = RC2 * t1, T22 = 2.f * RC6 * t2;
                float u0 = a1[0], u1 = a1[1], u2 = a1[2];
                float C300 = u1 * T02 - u2 * T01, C310 = u2 * T00 - u0 * T02, C320 = u0 * T01 - u1 * T00;
                float C301 = u1 * T12 - u2 * T11, C311 = u2 * T01 - u0 * T12, C321 = u0 * T11 - u1 * T01;
                float C302 = u1 * T22 - u2 * T12, C312 = u2 * T02 - u0 * T22, C322 = u0 * T12 - u1 * T02;
                TO5T(C300, C301, C302, C310, C311, C312, C320, C321, C322,
                     wl[8 + mm], 40 + mm);
                float P00 = T00 * A00 + T01 * A01 + T02 * A02;
                float P01 = T00 * A01 + T01 * A11 + T02 * A12;
                float P02 = T00 * A02 + T01 * A12 + T02 * A22;
                float P10 = T01 * A00 + T11 * A01 + T12 * A02;
                float P11 = T01 * A01 + T11 * A11 + T12 * A12;
                float P12 = T01 * A02 + T11 * A12 + T12 * A22;
                float P20 = T02 * A00 + T12 * A01 + T22 * A02;
                float P21 = T02 * A01 + T12 * A11 + T22 * A12;
                float P22 = T02 * A02 + T12 * A12 + T22 * A22;
                TO5T(P00, P01, P02, P10, P11, P12, P20, P21, P22,
                     wl[13 + mm], 45 + mm);
            }
        }
#undef TO5T
#undef ADDT
        const float kT = 0.1414213562373095f;
        float4* mrow = (float4*)(msgT + (size_t)e * 20);
#pragma unroll
        for (int i = 0; i < 5; i++) {
            float4 q;
            q.x = aT[4 * i] * kT; q.y = aT[4 * i + 1] * kT;
            q.z = aT[4 * i + 2] * kT; q.w = aT[4 * i + 3] * kT;
            mrow[i] = q;
        }
    }
#undef LERP4
#undef BUILD_MS
#undef BUILD_MV
#undef BUILD_MT
}

// ================= gather: wave per node over 3 compact msg arrays =================
__global__ __launch_bounds__(256) void gather_kernel(
    const float4* __restrict__ msgS4, const float4* __restrict__ msgV4,
    const float4* __restrict__ msgT4, const int* __restrict__ offs,
    const int* __restrict__ elist, float4* __restrict__ agg4)
{
    int wid = threadIdx.x >> 6;
    int lane = threadIdx.x & 63;
    int n = blockIdx.x * 4 + wid;
    if (n >= NN) return;
    int sub = lane / 18;
    int q = lane - sub * 18;
    const float4* base;
    int stride, qo;
    if (q < 7)       { base = msgS4; stride = 7; qo = q; }
    else if (q < 13) { base = msgV4; stride = 6; qo = q - 7; }
    else             { base = msgT4; stride = 5; qo = q - 13; }
    int beg = offs[n], end = offs[n + 1];
    float4 acc = {0.f, 0.f, 0.f, 0.f};
    if (sub < 3) {
        for (int j = beg + sub; j < end; j += 3) {
            int e = elist[j];
            float4 m = base[(size_t)e * stride + qo];
            acc.x += m.x; acc.y += m.y; acc.z += m.z; acc.w += m.w;
        }
    }
    float bx = __shfl(acc.x, lane + 18), by = __shfl(acc.y, lane + 18);
    float bz = __shfl(acc.z, lane + 18), bw = __shfl(acc.w, lane + 18);
    float cx = __shfl(acc.x, lane + 36), cy = __shfl(acc.y, lane + 36);
    float cz = __shfl(acc.z, lane + 36), cw = __shfl(acc.w, lane + 36);
    if (lane < 18) {
        float4 r;
        r.x = acc.x + bx + cx; r.y = acc.y + by + cy;
        r.z = acc.z + bz + cz; r.w = acc.w + bw + cw;
        agg4[(size_t)n * 18 + lane] = r;
    }
}

// ================= node update =================
__global__ __launch_bounds__(256) void node_kernel(
    const float* __restrict__ cur, const float* __restrict__ agg,
    const float* __restrict__ Wns, const float* __restrict__ Wnv, const float* __restrict__ Wnt,
    const float* __restrict__ Wps, const float* __restrict__ Wpv, const float* __restrict__ Wpt,
    float* __restrict__ dst)
{
    int n = blockIdx.x * 256 + threadIdx.x;
    if (n >= NN) return;
    const float* xn = cur + (size_t)n * FEAT;
    const float* ag = agg + (size_t)n * 72;
    const float invE = 0.0025f;

    float msv[28];
#pragma unroll
    for (int o = 0; o < 28; o++) msv[o] = ag[o] * invE;
#pragma unroll
    for (int i = 0; i < 16; i++) {
        float si = xn[i] * 0.25f;
#pragma unroll
        for (int o = 0; o < 28; o++) msv[o] += si * Wns[i * 28 + o];
    }
    float mvv[8][3];
#pragma unroll
    for (int o = 0; o < 8; o++)
#pragma unroll
        for (int c = 0; c < 3; c++) mvv[o][c] = ag[28 + o * 3 + c] * invE;
#pragma unroll
    for (int i = 0; i < 8; i++)
#pragma unroll
        for (int o = 0; o < 8; o++) {
            float w = Wnv[i * 8 + o] * 0.3535533905932738f;
#pragma unroll
            for (int c = 0; c < 3; c++) mvv[o][c] += xn[16 + i * 3 + c] * w;
        }
    float mtv[4][5];
#pragma unroll
    for (int o = 0; o < 4; o++)
#pragma unroll
        for (int c = 0; c < 5; c++) mtv[o][c] = ag[52 + o * 5 + c] * invE;
#pragma unroll
    for (int i = 0; i < 4; i++)
#pragma unroll
        for (int o = 0; o < 4; o++) {
            float w = Wnt[i * 4 + o] * 0.5f;
#pragma unroll
            for (int c = 0; c < 5; c++) mtv[o][c] += xn[40 + i * 5 + c] * w;
        }

    float g[12];
#pragma unroll
    for (int j = 0; j < 12; j++) g[j] = sigmoidf_(msv[16 + j]);
    float hs[16];
#pragma unroll
    for (int i = 0; i < 16; i++) hs[i] = geluf(msv[i]);

    float outv[60];
#pragma unroll
    for (int o = 0; o < 16; o++) outv[o] = 0.f;
#pragma unroll
    for (int i = 0; i < 16; i++) {
        float si = hs[i] * 0.25f;
#pragma unroll
        for (int o = 0; o < 16; o++) outv[o] += si * Wps[i * 16 + o];
    }
#pragma unroll
    for (int o = 0; o < 8; o++)
#pragma unroll
        for (int c = 0; c < 3; c++) outv[16 + o * 3 + c] = 0.f;
#pragma unroll
    for (int i = 0; i < 8; i++) {
        float gi = g[i];
#pragma unroll
        for (int o = 0; o < 8; o++) {
            float w = Wpv[i * 8 + o] * 0.3535533905932738f * gi;
#pragma unroll
            for (int c = 0; c < 3; c++) outv[16 + o * 3 + c] += mvv[i][c] * w;
        }
    }
#pragma unroll
    for (int o = 0; o < 4; o++)
#pragma unroll
        for (int c = 0; c < 5; c++) outv[40 + o * 5 + c] = 0.f;
#pragma unroll
    for (int i = 0; i < 4; i++) {
        float gi = g[8 + i];
#pragma unroll
        for (int o = 0; o < 4; o++) {
            float w = Wpt[i * 4 + o] * 0.5f * gi;
#pragma unroll
            for (int c = 0; c < 5; c++) outv[40 + o * 5 + c] += mtv[i][c] * w;
        }
    }

    float4* dst4 = (float4*)(dst + (size_t)n * FEAT);
#pragma unroll
    for (int i = 0; i < 15; i++) {
        float4 q;
        q.x = outv[4 * i]; q.y = outv[4 * i + 1]; q.z = outv[4 * i + 2]; q.w = outv[4 * i + 3];
        dst4[i] = q;
    }
}

// ================= host =================
static inline size_t algn(size_t o) { return (o + 63) & ~(size_t)63; }

extern "C" void kernel_launch(void* const* d_in, const int* in_sizes, int n_in,
                              void* d_out, int out_size, void* d_ws, size_t ws_size,
                              hipStream_t stream)
{
    const float* x    = (const float*)d_in[0];
    const float* Wl_s = (const float*)d_in[1];
    const float* Wl_v = (const float*)d_in[2];
    const float* Wl_t = (const float*)d_in[3];
    const float* Wr0  = (const float*)d_in[4];
    const float* Wr1  = (const float*)d_in[5];
    const float* Wr2  = (const float*)d_in[6];
    const float* Wr3  = (const float*)d_in[7];
    const float* Wm_s = (const float*)d_in[8];
    const float* Wm_v = (const float*)d_in[9];
    const float* Wm_t = (const float*)d_in[10];
    const float* Wn_s = (const float*)d_in[11];
    const float* Wn_v = (const float*)d_in[12];
    const float* Wn_t = (const float*)d_in[13];
    const float* Wp_s = (const float*)d_in[14];
    const float* Wp_v = (const float*)d_in[15];
    const float* Wp_t = (const float*)d_in[16];
    const int* snd = (const int*)d_in[17];
    const int* rcv = (const int*)d_in[18];
    float* out = (float*)d_out;

    char* ws = (char*)d_ws;
    size_t off = 0;
    float* cur    = (float*)(ws + off); off = algn(off + (size_t)NN * FEAT * 4);
    float* agg    = (float*)(ws + off); off = algn(off + (size_t)NN * 72 * 4);
    float* msgS   = (float*)(ws + off); off = algn(off + (size_t)NE * 28 * 4);
    float* msgV   = (float*)(ws + off); off = algn(off + (size_t)NE * 24 * 4);
    float* msgT   = (float*)(ws + off); off = algn(off + (size_t)NE * 20 * 4);
    int*   counts = (int*)(ws + off);   off = algn(off + (size_t)NN * 4);
    int*   offs   = (int*)(ws + off);   off = algn(off + (size_t)(NN + 1) * 4);
    int*   rank   = (int*)(ws + off);   off = algn(off + (size_t)NE * 4);
    int*   elist  = (int*)(ws + off);   off = algn(off + (size_t)NE * 4);
    float* W3t    = (float*)(ws + off); off = algn(off + (size_t)3 * NIR * DH * 4);
    float* table  = (float*)(ws + off); off = algn(off + (size_t)ENT * ROWF * 4);

    hipMemcpyAsync(cur, x, (size_t)NN * FEAT * 4, hipMemcpyDeviceToDevice, stream);
    hipMemsetAsync(counts, 0, (size_t)NN * 4, stream);
    int nb = (NE + 255) / 256;
    csr_hist<<<nb, 256, 0, stream>>>(rcv, counts, rank);
    csr_scan<<<1, 1024, 0, stream>>>(counts, offs);
    csr_fill<<<nb, 256, 0, stream>>>(rcv, offs, rank, elist);
    w3t_kernel<<<(3 * NIR * DH + 255) / 256, 256, 0, stream>>>(Wr3, W3t);

    for (int k = 0; k < 3; k++) {
        const float* W0  = Wr0 + (size_t)k * 4 * DH;
        const float* W1  = Wr1 + (size_t)k * DH * DH;
        const float* W2  = Wr2 + (size_t)k * DH * DH;
        const float* W3tk= W3t + (size_t)k * NIR * DH;
        const float* Wls = Wl_s + (size_t)k * 16 * 16;
        const float* Wlv = Wl_v + (size_t)k * 8 * 8;
        const float* Wlt = Wl_t + (size_t)k * 4 * 4;
        const float* Wms = Wm_s + (size_t)k * SC * 28;
        const float* Wmv = Wm_v + (size_t)k * VC * 8;
        const float* Wmt = Wm_t + (size_t)k * TC * 4;
        const float* Wns = Wn_s + (size_t)k * 16 * 28;
        const float* Wnv = Wn_v + (size_t)k * 8 * 8;
        const float* Wnt = Wn_t + (size_t)k * 4 * 4;
        const float* Wps = Wp_s + (size_t)k * 16 * 16;
        const float* Wpv = Wp_v + (size_t)k * 8 * 8;
        const float* Wpt = Wp_t + (size_t)k * 4 * 4;

        table_kernel<<<ENT / 4, 256, 0, stream>>>(W0, W1, W2, W3tk, table);
        tp3_kernel<<<3 * nb, 256, 0, stream>>>(cur, snd, rcv, Wls, Wlv, Wlt,
                                               Wms, Wmv, Wmt, (const float4*)table,
                                               msgS, msgV, msgT, nb);
        gather_kernel<<<(NN + 3) / 4, 256, 0, stream>>>(
            (const float4*)msgS, (const float4*)msgV, (const float4*)msgT,
            offs, elist, (float4*)agg);
        float* dst = (k == 2) ? out : cur;
        node_kernel<<<(NN + 255) / 256, 256, 0, stream>>>(cur, agg, Wns, Wnv, Wnt,
                                                          Wps, Wpv, Wpt, dst);
    }
}